// Round 1
// baseline (881.099 us; speedup 1.0000x reference)
//
#include <hip/hip_runtime.h>

// Problem constants (match reference)
constexpr int   N_POINTS     = 262144;
constexpr int   FEAT_DIM     = 512;
constexpr int   NUM_NEG      = 8;
constexpr int   IGNORE_LABEL = 255;
constexpr float NEG_THRESH   = 0.85f;
constexpr float POS_THRESH   = 0.0f;
constexpr float EPS          = 1e-7f;

// d_out layout (reference returns (loss, pos_loss, neg_loss)):
//   out[0]                      = loss (scalar)
//   out[1 .. N]                 = pos_loss
//   out[1+N .. 1+2N]            = neg_loss

__global__ void zero_ws_kernel(float* ws) {
    ws[0] = 0.f;  // sum of pos_loss
    ws[1] = 0.f;  // sum of neg_loss
}

// One wave (64 lanes) per point, grid-stride. Each lane owns 8 feature
// elements as two float4 loads (lane and lane+64 in float4 units -> fully
// coalesced 1 KiB per instruction per wave). Anchor rows are gathered the
// same way; the 400 KB anchor table is L2-resident.
__global__ __launch_bounds__(256, 4) void ccl_main_kernel(
    const float* __restrict__ features,   // [N, 512]
    const int*   __restrict__ labels,     // [N]
    const float* __restrict__ anchors,    // [200, 512]
    const int*   __restrict__ neg_inds,   // [N, 8]
    float*       __restrict__ out,        // [1 + 2N]
    float*       __restrict__ ws)         // [2] partial sums
{
    const int lane   = threadIdx.x & 63;
    const int wid    = threadIdx.x >> 6;          // wave in block (0..3)
    const int gwave  = blockIdx.x * 4 + wid;
    const int nwaves = gridDim.x * 4;

    float* pos_out = out + 1;
    float* neg_out = out + 1 + N_POINTS;

    float sum_pos = 0.f, sum_neg = 0.f;

    for (int p = gwave; p < N_POINTS; p += nwaves) {
        const float4* frow = (const float4*)(features + (size_t)p * FEAT_DIM);
        const float4 fa = frow[lane];
        const float4 fb = frow[lane + 64];

        const int  lab   = labels[p];
        const bool valid = (lab != IGNORE_LABEL);

        int idx[9];
        idx[0] = valid ? lab : 0;   // guard OOB gather for ignore-label rows
#pragma unroll
        for (int k = 0; k < NUM_NEG; ++k)
            idx[k + 1] = neg_inds[(size_t)p * NUM_NEG + k];

        float d2[9];
#pragma unroll
        for (int k = 0; k < 9; ++k) {
            const float4* arow = (const float4*)(anchors + (size_t)idx[k] * FEAT_DIM);
            const float4 aa = arow[lane];
            const float4 ab = arow[lane + 64];
            float s, dx;
            dx = fa.x - aa.x; s  = dx * dx;
            dx = fa.y - aa.y; s  = fmaf(dx, dx, s);
            dx = fa.z - aa.z; s  = fmaf(dx, dx, s);
            dx = fa.w - aa.w; s  = fmaf(dx, dx, s);
            dx = fb.x - ab.x; s  = fmaf(dx, dx, s);
            dx = fb.y - ab.y; s  = fmaf(dx, dx, s);
            dx = fb.z - ab.z; s  = fmaf(dx, dx, s);
            dx = fb.w - ab.w; s  = fmaf(dx, dx, s);
            d2[k] = s;
        }

        // Butterfly-reduce each of the 9 partials across the 64-lane wave.
#pragma unroll
        for (int k = 0; k < 9; ++k) {
            float v = d2[k];
#pragma unroll
            for (int off = 32; off > 0; off >>= 1)
                v += __shfl_xor(v, off, 64);
            d2[k] = v;
        }

        float pos_dist = sqrtf(d2[0] + EPS);   // d2 >= 0 by construction
        float acc = 0.f;
#pragma unroll
        for (int k = 1; k < 9; ++k)
            acc += sqrtf(d2[k] + EPS);
        float neg_dist = acc * (1.0f / NUM_NEG);

        if (!valid) { pos_dist = 0.f; neg_dist = 0.f; }

        const float pos_loss = fmaxf(pos_dist - POS_THRESH, 0.f);
        const float neg_loss = fmaxf(NEG_THRESH - neg_dist, 0.f);

        if (lane == 0) {
            pos_out[p] = pos_loss;
            neg_out[p] = neg_loss;
            sum_pos += pos_loss;
            sum_neg += neg_loss;
        }
    }

    // Block reduction of the 4 wave-lane0 partials, one atomicAdd per block.
    __shared__ float sp[4], sn[4];
    if (lane == 0) { sp[wid] = sum_pos; sn[wid] = sum_neg; }
    __syncthreads();
    if (threadIdx.x == 0) {
        atomicAdd(&ws[0], sp[0] + sp[1] + sp[2] + sp[3]);
        atomicAdd(&ws[1], sn[0] + sn[1] + sn[2] + sn[3]);
    }
}

__global__ void finalize_kernel(const float* __restrict__ ws,
                                float* __restrict__ out) {
    // loss = mean(pos_loss) + mean(neg_loss) * NEG_WEIGHT (NEG_WEIGHT = 1)
    out[0] = (ws[0] + ws[1]) * (1.0f / (float)N_POINTS);
}

extern "C" void kernel_launch(void* const* d_in, const int* in_sizes, int n_in,
                              void* d_out, int out_size, void* d_ws, size_t ws_size,
                              hipStream_t stream) {
    const float* features = (const float*)d_in[0];
    const int*   labels   = (const int*)  d_in[1];
    const float* anchors  = (const float*)d_in[2];
    const int*   neg_inds = (const int*)  d_in[3];
    float* out = (float*)d_out;
    float* ws  = (float*)d_ws;

    zero_ws_kernel<<<1, 1, 0, stream>>>(ws);

    // 4096 blocks x 4 waves = 16384 waves -> 16 points per wave grid-stride.
    ccl_main_kernel<<<4096, 256, 0, stream>>>(features, labels, anchors,
                                              neg_inds, out, ws);

    finalize_kernel<<<1, 1, 0, stream>>>(ws, out);
}